// Round 1
// baseline (915.258 us; speedup 1.0000x reference)
//
#include <hip/hip_runtime.h>
#include <math.h>

// Problem constants
#define R_  128
#define C_  256
#define E_  768
#define H_  12
#define DK_ 64
#define T_  (R_*C_)       // 32768 tokens
#define RS_ 8             // split-K over rows in attn kernel
#define LP  40            // LDS pitch for ctx_mfma only (legacy padded layout)

typedef __attribute__((ext_vector_type(8))) short          bf16x8;
typedef __attribute__((ext_vector_type(4))) float          f32x4;
typedef __attribute__((ext_vector_type(4))) unsigned short u16x4;
typedef __attribute__((ext_vector_type(8))) unsigned short u16x8;

struct HL { unsigned short h, l; };

// fp32 -> (hi, lo) bf16 split via truncation. hi+lo represents f with ~2^-16
// relative error; lo = f - hi is exact in fp32 (Sterbenz), then truncated.
__device__ __forceinline__ HL split2(float f) {
    HL o;
    unsigned int u = __float_as_uint(f);
    o.h = (unsigned short)(u >> 16);
    float r = f - __uint_as_float(u & 0xFFFF0000u);
    o.l = (unsigned short)(__float_as_uint(r) >> 16);
    return o;
}

// async global->LDS, 16 B per lane. LDS dest is wave-uniform base + lane*16.
__device__ __forceinline__ void gload16(const void* g, void* l) {
    __builtin_amdgcn_global_load_lds(
        (const __attribute__((address_space(1))) unsigned int*)g,
        (__attribute__((address_space(3))) unsigned int*)l,
        16, 0, 0);
}

// ---------------------------------------------------------------------------
// Pre-split: fp32 -> planar (hi, lo) bf16. 8 elems/thread, exact grids only.
// ---------------------------------------------------------------------------
__global__ __launch_bounds__(256) void split_kernel(
    const float* __restrict__ src,
    unsigned short* __restrict__ h, unsigned short* __restrict__ l)
{
    const size_t i = ((size_t)blockIdx.x * 256 + threadIdx.x) * 8;
    float4 f0 = *(const float4*)(src + i);
    float4 f1 = *(const float4*)(src + i + 4);
    float v[8] = { f0.x, f0.y, f0.z, f0.w, f1.x, f1.y, f1.z, f1.w };
    u16x8 hh, ll;
    #pragma unroll
    for (int j = 0; j < 8; ++j) { HL e = split2(v[j]); hh[j] = e.h; ll[j] = e.l; }
    *(u16x8*)(h + i) = hh;
    *(u16x8*)(l + i) = ll;
}

// ---------------------------------------------------------------------------
// GEMM: Y[m,n] = (sum_k A[m,k]*B[n,k] + bias[n]) * scale
// All operands pre-split planar bf16 (Ah/Al, Bh/Bl). M x 768 x 768,
// 128x128 block tile, BK=32, 256 threads (2x2 waves of 64x64 wave tiles),
// mfma_f32_16x16x32_bf16 with 3-term hi/lo product.
//
// Staging: wave w stages tile w (AsH/AsL/BsH/BsL) via 8x global_load_lds
// (16 B/lane, 1024 B/instr = 16 rows of the linear [128][32]-ushort tile).
// LDS swizzle: granule g (8 ushorts) of row r sits at slot g ^ ((r>>1)&3),
// realized by permuting the per-lane GLOBAL source address (LDS dest linear,
// as gload_lds requires). Reads XOR the same term -> bank-start
// (fr&1)*16 + (g^((fr>>1)&3))*4 covers all banks uniformly: conflict-free.
// OMODE 0: write split output (Yh, Yl).  OMODE 1: write fp32 Y.
// ---------------------------------------------------------------------------
template<int OMODE>
__global__ __launch_bounds__(256, 2) void gemm_kernel(
    const unsigned short* __restrict__ Ah, const unsigned short* __restrict__ Al,
    const unsigned short* __restrict__ Bh, const unsigned short* __restrict__ Bl,
    const float* __restrict__ bias, float scale,
    float* __restrict__ Y32, unsigned short* __restrict__ Yh, unsigned short* __restrict__ Yl)
{
    __shared__ __align__(16) unsigned short smem[16384];   // 32 KB: 4 x [128][32]
    const unsigned short* AsH = smem;
    const unsigned short* AsL = smem + 4096;
    const unsigned short* BsH = smem + 8192;
    const unsigned short* BsL = smem + 12288;

    const int tid  = threadIdx.x;
    const int m0   = blockIdx.x * 128;
    const int n0   = blockIdx.y * 128;
    const int wave = tid >> 6, lane = tid & 63;
    const int wm   = (wave & 1) * 64, wn = (wave >> 1) * 64;
    const int fr   = lane & 15;
    // swizzled read k-offset (ushorts): granule lane>>4 lives at slot ^((fr>>1)&3)
    const int kqs  = (((lane >> 4) ^ ((fr >> 1) & 3)) * 8);

    // staging: lane -> (row = l>>2, slot = l&3); source granule = slot ^ ((l>>3)&3)
    const int lrow = lane >> 2;
    const int gd   = (lane & 3) ^ ((lane >> 3) & 3);
    const unsigned short* gsrc = (wave == 0) ? Ah : (wave == 1) ? Al
                               : (wave == 2) ? Bh : Bl;
    const int rbase = (wave < 2) ? m0 : n0;
    unsigned short* lt = smem + wave * 4096;
    const unsigned short* sp = gsrc + (size_t)(rbase + lrow) * E_ + 8 * gd;

    f32x4 acc[4][4] = {};

    for (int k0 = 0; k0 < E_; k0 += 32) {
        #pragma unroll
        for (int i = 0; i < 8; ++i)
            gload16(sp + k0 + (size_t)i * 16 * E_, lt + i * 512);
        __syncthreads();   // compiler drains vmcnt(0) before s_barrier

        bf16x8 a_h[4], a_l[4], b_h[4], b_l[4];
        #pragma unroll
        for (int t = 0; t < 4; ++t) {
            a_h[t] = *(const bf16x8*)&AsH[(wm + t * 16 + fr) * 32 + kqs];
            a_l[t] = *(const bf16x8*)&AsL[(wm + t * 16 + fr) * 32 + kqs];
            b_h[t] = *(const bf16x8*)&BsH[(wn + t * 16 + fr) * 32 + kqs];
            b_l[t] = *(const bf16x8*)&BsL[(wn + t * 16 + fr) * 32 + kqs];
        }
        #pragma unroll
        for (int i = 0; i < 4; ++i)
            #pragma unroll
            for (int j = 0; j < 4; ++j) {
                acc[i][j] = __builtin_amdgcn_mfma_f32_16x16x32_bf16(a_h[i], b_h[j], acc[i][j], 0, 0, 0);
                acc[i][j] = __builtin_amdgcn_mfma_f32_16x16x32_bf16(a_h[i], b_l[j], acc[i][j], 0, 0, 0);
                acc[i][j] = __builtin_amdgcn_mfma_f32_16x16x32_bf16(a_l[i], b_h[j], acc[i][j], 0, 0, 0);
            }
        __syncthreads();
    }

    // ---- epilogue: per-wave LDS repack -> wide coalesced stores ----
    float* rep = (float*)smem + wave * 1024;   // [16][64] per wave
    const int mr = lane >> 2;
    const int nc = (lane & 3) * 16;
    #pragma unroll
    for (int ti = 0; ti < 4; ++ti) {
        __syncthreads();
        #pragma unroll
        for (int tj = 0; tj < 4; ++tj)
            #pragma unroll
            for (int r = 0; r < 4; ++r)
                rep[((lane >> 4) * 4 + r) * 64 + tj * 16 + fr] = acc[ti][tj][r];
        __syncthreads();
        float v[16];
        #pragma unroll
        for (int c = 0; c < 4; ++c)
            *(float4*)&v[4 * c] = *(const float4*)&rep[mr * 64 + nc + 4 * c];
        const int gm = m0 + wm + ti * 16 + mr;
        const int gn = n0 + wn + nc;
        if constexpr (OMODE == 1) {
            #pragma unroll
            for (int c = 0; c < 4; ++c) {
                float4 bv = *(const float4*)&bias[gn + 4 * c];
                float4 o;
                o.x = (v[4*c+0] + bv.x) * scale; o.y = (v[4*c+1] + bv.y) * scale;
                o.z = (v[4*c+2] + bv.z) * scale; o.w = (v[4*c+3] + bv.w) * scale;
                *(float4*)&Y32[(size_t)gm * E_ + gn + 4 * c] = o;
            }
        } else {
            unsigned short hh[16], ll[16];
            #pragma unroll
            for (int c = 0; c < 4; ++c) {
                float4 bv = *(const float4*)&bias[gn + 4 * c];
                HL e0 = split2((v[4*c+0] + bv.x) * scale);
                HL e1 = split2((v[4*c+1] + bv.y) * scale);
                HL e2 = split2((v[4*c+2] + bv.z) * scale);
                HL e3 = split2((v[4*c+3] + bv.w) * scale);
                hh[4*c+0] = e0.h; ll[4*c+0] = e0.l;
                hh[4*c+1] = e1.h; ll[4*c+1] = e1.l;
                hh[4*c+2] = e2.h; ll[4*c+2] = e2.l;
                hh[4*c+3] = e3.h; ll[4*c+3] = e3.l;
            }
            u16x8 H0, H1, L0, L1;
            #pragma unroll
            for (int j = 0; j < 8; ++j) { H0[j] = hh[j]; H1[j] = hh[8+j]; L0[j] = ll[j]; L1[j] = ll[8+j]; }
            *(u16x8*)&Yh[(size_t)gm * E_ + gn]     = H0;
            *(u16x8*)&Yh[(size_t)gm * E_ + gn + 8] = H1;
            *(u16x8*)&Yl[(size_t)gm * E_ + gn]     = L0;
            *(u16x8*)&Yl[(size_t)gm * E_ + gn + 8] = L1;
        }
    }
}

// ---------------------------------------------------------------------------
// Pooled attention logits, split-K over rows: part[rc,h,i,j] =
//   sum_{r in chunk rc} sum_d q[r,i,h,d] * k[r,j,h,d]
// 128x128 (i,j) tile per block, K-chunk = 16 rows * 64 d = 1024 (32 steps).
// Same gload_lds + swizzle staging as gemm_kernel (wave w stages tile w).
// ---------------------------------------------------------------------------
__global__ __launch_bounds__(256, 2) void attn_mfma(
    const unsigned short* __restrict__ Qh, const unsigned short* __restrict__ Ql,
    const unsigned short* __restrict__ Kh, const unsigned short* __restrict__ Kl,
    float* __restrict__ part)
{
    __shared__ __align__(16) unsigned short smem[16384];
    const unsigned short* AsH = smem;
    const unsigned short* AsL = smem + 4096;
    const unsigned short* BsH = smem + 8192;
    const unsigned short* BsL = smem + 12288;

    const int tid  = threadIdx.x;
    const int i0   = blockIdx.x * 128;
    const int j0   = blockIdx.y * 128;
    const int hz   = blockIdx.z;          // h * RS_ + rc
    const int h    = hz >> 3;
    const int rc   = hz & 7;
    const int wave = tid >> 6, lane = tid & 63;
    const int wm   = (wave & 1) * 64, wn = (wave >> 1) * 64;
    const int fr   = lane & 15;
    const int kqs  = (((lane >> 4) ^ ((fr >> 1) & 3)) * 8);

    const int lrow = lane >> 2;
    const int gd   = (lane & 3) ^ ((lane >> 3) & 3);
    const unsigned short* gsrc = (wave == 0) ? Qh : (wave == 1) ? Ql
                               : (wave == 2) ? Kh : Kl;
    const int rbase = (wave < 2) ? i0 : j0;
    unsigned short* lt = smem + wave * 4096;

    f32x4 acc[4][4] = {};

    for (int s = 0; s < 32; ++s) {
        const int r  = rc * 16 + (s >> 1);
        const int d0 = (s & 1) * 32;
        const unsigned short* sp =
            gsrc + ((size_t)(r * C_) + rbase + lrow) * E_ + h * DK_ + d0 + 8 * gd;
        #pragma unroll
        for (int i = 0; i < 8; ++i)
            gload16(sp + (size_t)i * 16 * E_, lt + i * 512);
        __syncthreads();

        bf16x8 a_h[4], a_l[4], b_h[4], b_l[4];
        #pragma unroll
        for (int t = 0; t < 4; ++t) {
            a_h[t] = *(const bf16x8*)&AsH[(wm + t * 16 + fr) * 32 + kqs];
            a_l[t] = *(const bf16x8*)&AsL[(wm + t * 16 + fr) * 32 + kqs];
            b_h[t] = *(const bf16x8*)&BsH[(wn + t * 16 + fr) * 32 + kqs];
            b_l[t] = *(const bf16x8*)&BsL[(wn + t * 16 + fr) * 32 + kqs];
        }
        #pragma unroll
        for (int i = 0; i < 4; ++i)
            #pragma unroll
            for (int j = 0; j < 4; ++j) {
                acc[i][j] = __builtin_amdgcn_mfma_f32_16x16x32_bf16(a_h[i], b_h[j], acc[i][j], 0, 0, 0);
                acc[i][j] = __builtin_amdgcn_mfma_f32_16x16x32_bf16(a_h[i], b_l[j], acc[i][j], 0, 0, 0);
                acc[i][j] = __builtin_amdgcn_mfma_f32_16x16x32_bf16(a_l[i], b_h[j], acc[i][j], 0, 0, 0);
            }
        __syncthreads();
    }

    float* rep = (float*)smem + wave * 1024;
    const int mr = lane >> 2;
    const int nc = (lane & 3) * 16;
    #pragma unroll
    for (int ti = 0; ti < 4; ++ti) {
        __syncthreads();
        #pragma unroll
        for (int tj = 0; tj < 4; ++tj)
            #pragma unroll
            for (int r = 0; r < 4; ++r)
                rep[((lane >> 4) * 4 + r) * 64 + tj * 16 + fr] = acc[ti][tj][r];
        __syncthreads();
        const int gi = i0 + wm + ti * 16 + mr;
        const int gj = j0 + wn + nc;
        #pragma unroll
        for (int c = 0; c < 4; ++c) {
            float4 o = *(const float4*)&rep[mr * 64 + nc + 4 * c];
            *(float4*)&part[((size_t)(rc * H_ + h) * C_ + gi) * C_ + gj + 4 * c] = o;
        }
    }
}

// ---------------------------------------------------------------------------
// Reduce RS_ partials + row softmax + write fp32 probs and bf16 split.
// One 256-thread block per (h, i) row.
// ---------------------------------------------------------------------------
__global__ __launch_bounds__(256) void softmax_split(
    const float* __restrict__ part, float* __restrict__ probs,
    unsigned short* __restrict__ ph, unsigned short* __restrict__ pl)
{
    const int row = blockIdx.x;            // h * C_ + i
    const int j = threadIdx.x;
    const int wave = j >> 6, lane = j & 63;

    float s = 0.0f;
    #pragma unroll
    for (int rcn = 0; rcn < RS_; ++rcn)
        s += part[((size_t)rcn * H_ * C_ + row) * C_ + j];

    float m = s;
    #pragma unroll
    for (int off = 32; off > 0; off >>= 1)
        m = fmaxf(m, __shfl_down(m, off, 64));
    __shared__ float redm[4];
    if (lane == 0) redm[wave] = m;
    __syncthreads();
    m = fmaxf(fmaxf(redm[0], redm[1]), fmaxf(redm[2], redm[3]));

    float e = expf(s - m);
    float t = e;
    #pragma unroll
    for (int off = 32; off > 0; off >>= 1)
        t += __shfl_down(t, off, 64);
    __shared__ float reds[4];
    if (lane == 0) reds[wave] = t;
    __syncthreads();
    t = reds[0] + reds[1] + reds[2] + reds[3];

    float p = e / t;
    probs[(size_t)row * C_ + j] = p;
    HL sp = split2(p);
    ph[(size_t)row * C_ + j] = sp.h;
    pl[(size_t)row * C_ + j] = sp.l;
}

// ---------------------------------------------------------------------------
// Context: C[r*C+i, h*64+d] = sum_j P[h,i,j] * V[r*C+j, h*64+d], split output.
// Per (i-block, r, h): M=128(i), N=64(d), K=256(j), BK=32 -> 8 steps.
// V staged transposed into LDS ([d][j]).  (Unchanged this round.)
// ---------------------------------------------------------------------------
__global__ __launch_bounds__(256, 2) void ctx_mfma(
    const unsigned short* __restrict__ Ph, const unsigned short* __restrict__ Pl,
    const unsigned short* __restrict__ Vh, const unsigned short* __restrict__ Vl,
    unsigned short* __restrict__ Ch, unsigned short* __restrict__ Cl)
{
    __shared__ __align__(16) unsigned short smem[15360];   // 30 KB
    unsigned short* PsH = smem;            // [128][LP]
    unsigned short* PsL = smem + 5120;
    unsigned short* VsH = smem + 10240;    // [64][LP]
    unsigned short* VsL = smem + 12800;

    const int tid  = threadIdx.x;
    const int i0   = blockIdx.x * 128;
    const int r    = blockIdx.y;
    const int h    = blockIdx.z;
    const int wave = tid >> 6, lane = tid & 63;
    const int wm   = (wave & 1) * 64, wn = (wave >> 1) * 32;
    const int fr   = lane & 15;
    const int kq   = (lane >> 4) * 8;
    const int srow = tid >> 1;
    const int sk   = (tid & 1) * 16;
    const int vjj  = tid & 31;
    const int vdg  = tid >> 5;             // 0..7

    f32x4 acc[4][2] = {};

    for (int s = 0; s < 8; ++s) {
        const int jb = s * 32;
        const size_t pb = ((size_t)(h * C_) + i0 + srow) * C_ + jb + sk;
        *(u16x8*)&PsH[srow * LP + sk]     = *(const u16x8*)&Ph[pb];
        *(u16x8*)&PsH[srow * LP + sk + 8] = *(const u16x8*)&Ph[pb + 8];
        *(u16x8*)&PsL[srow * LP + sk]     = *(const u16x8*)&Pl[pb];
        *(u16x8*)&PsL[srow * LP + sk + 8] = *(const u16x8*)&Pl[pb + 8];
        const size_t vb = ((size_t)(r * C_) + jb + vjj) * E_ + h * DK_ + vdg * 8;
        u16x8 v_h = *(const u16x8*)&Vh[vb];
        u16x8 v_l = *(const u16x8*)&Vl[vb];
        #pragma unroll
        for (int u = 0; u < 8; ++u) {
            VsH[(vdg * 8 + u) * LP + vjj] = v_h[u];
            VsL[(vdg * 8 + u) * LP + vjj] = v_l[u];
        }
        __syncthreads();

        bf16x8 p_h[4], p_l[4], w_h[2], w_l[2];
        #pragma unroll
        for (int t = 0; t < 4; ++t) {
            p_h[t] = *(const bf16x8*)&PsH[(wm + t * 16 + fr) * LP + kq];
            p_l[t] = *(const bf16x8*)&PsL[(wm + t * 16 + fr) * LP + kq];
        }
        #pragma unroll
        for (int t = 0; t < 2; ++t) {
            w_h[t] = *(const bf16x8*)&VsH[(wn + t * 16 + fr) * LP + kq];
            w_l[t] = *(const bf16x8*)&VsL[(wn + t * 16 + fr) * LP + kq];
        }
        #pragma unroll
        for (int i = 0; i < 4; ++i)
            #pragma unroll
            for (int j = 0; j < 2; ++j) {
                acc[i][j] = __builtin_amdgcn_mfma_f32_16x16x32_bf16(p_h[i], w_h[j], acc[i][j], 0, 0, 0);
                acc[i][j] = __builtin_amdgcn_mfma_f32_16x16x32_bf16(p_h[i], w_l[j], acc[i][j], 0, 0, 0);
                acc[i][j] = __builtin_amdgcn_mfma_f32_16x16x32_bf16(p_l[i], w_h[j], acc[i][j], 0, 0, 0);
            }
        __syncthreads();
    }

    float* rep = (float*)smem + wave * 512;   // [16][32] per wave
    const int mr = lane >> 2;
    const int nc = (lane & 3) * 8;
    #pragma unroll
    for (int ti = 0; ti < 4; ++ti) {
        __syncthreads();
        #pragma unroll
        for (int tj = 0; tj < 2; ++tj)
            #pragma unroll
            for (int rr = 0; rr < 4; ++rr)
                rep[((lane >> 4) * 4 + rr) * 32 + tj * 16 + fr] = acc[ti][tj][rr];
        __syncthreads();
        float v[8];
        *(float4*)&v[0] = *(const float4*)&rep[mr * 32 + nc];
        *(float4*)&v[4] = *(const float4*)&rep[mr * 32 + nc + 4];
        const int gm = r * C_ + i0 + wm + ti * 16 + mr;
        const int gn = h * DK_ + wn + nc;
        u16x8 H8, L8;
        #pragma unroll
        for (int jj = 0; jj < 8; ++jj) { HL e = split2(v[jj]); H8[jj] = e.h; L8[jj] = e.l; }
        *(u16x8*)&Ch[(size_t)gm * E_ + gn] = H8;
        *(u16x8*)&Cl[(size_t)gm * E_ + gn] = L8;
    }
}

// ---------------------------------------------------------------------------
extern "C" void kernel_launch(void* const* d_in, const int* in_sizes, int n_in,
                              void* d_out, int out_size, void* d_ws, size_t ws_size,
                              hipStream_t stream)
{
    (void)in_sizes; (void)n_in; (void)out_size; (void)ws_size;

    const float* x  = (const float*)d_in[0];
    const float* Wq = (const float*)d_in[1];
    const float* bq = (const float*)d_in[2];
    const float* Wk = (const float*)d_in[3];
    const float* bk = (const float*)d_in[4];
    const float* Wv = (const float*)d_in[5];
    const float* bv = (const float*)d_in[6];
    const float* Wo = (const float*)d_in[7];
    const float* bo = (const float*)d_in[8];

    float* out   = (float*)d_out;
    float* probs = out + (size_t)T_ * E_;
    float* part  = out;                     // scratch: out region free until attn

    // ws: 6 planar bf16 buffers of T_*E_ ushorts = 302 MB (unchanged).
    const size_t QN = (size_t)T_ * E_;
    const size_t WN = (size_t)E_ * E_;
    unsigned short* qh = (unsigned short*)d_ws;
    unsigned short* ql = qh + QN;
    unsigned short* kh = ql + QN;
    unsigned short* kl = kh + QN;
    unsigned short* vh = kl + QN;
    unsigned short* vl = vh + QN;
    unsigned short* ph = kh;                 // reuse kh plane (dead after attn)
    unsigned short* pl = kh + (size_t)H_ * C_ * C_;
    unsigned short* ch = qh;                 // reuse q planes (dead after attn)
    unsigned short* cl = ql;

    // Scratch overlays (no new workspace):
    //   xh/xl   -> out region [0, 100.7 MB): dead before attn writes `part`.
    //   wsph/l  -> probs tail region (3.1 MB): dead before softmax writes probs.
    //   woh/wol -> kl plane: dead after attn, survives softmax/ctx/gemm4.
    unsigned short* xh   = (unsigned short*)out;
    unsigned short* xl   = xh + QN;
    unsigned short* wsph = (unsigned short*)probs;
    unsigned short* wspl = wsph + WN;
    unsigned short* woh  = kl;
    unsigned short* wol  = kl + WN;

    const float scaling = 0.125f / sqrtf(128.0f);   // DK^-0.5 / sqrt(R)

    dim3 blk(256);
    const int xblocks = (int)(QN / 2048);   // 8 elems/thread, exact
    const int wblocks = (int)(WN / 2048);

    split_kernel<<<dim3(xblocks), blk, 0, stream>>>(x, xh, xl);

    split_kernel<<<dim3(wblocks), blk, 0, stream>>>(Wq, wsph, wspl);
    gemm_kernel<0><<<dim3(T_ / 128, E_ / 128), blk, 0, stream>>>(
        xh, xl, wsph, wspl, bq, scaling, nullptr, qh, ql);

    split_kernel<<<dim3(wblocks), blk, 0, stream>>>(Wk, wsph, wspl);
    gemm_kernel<0><<<dim3(T_ / 128, E_ / 128), blk, 0, stream>>>(
        xh, xl, wsph, wspl, bk, 1.0f, nullptr, kh, kl);

    split_kernel<<<dim3(wblocks), blk, 0, stream>>>(Wv, wsph, wspl);
    gemm_kernel<0><<<dim3(T_ / 128, E_ / 128), blk, 0, stream>>>(
        xh, xl, wsph, wspl, bv, 1.0f, nullptr, vh, vl);

    attn_mfma<<<dim3(C_ / 128, C_ / 128, H_ * RS_), blk, 0, stream>>>(qh, ql, kh, kl, part);

    split_kernel<<<dim3(wblocks), blk, 0, stream>>>(Wo, woh, wol);   // kl plane now dead

    softmax_split<<<dim3(H_ * C_), blk, 0, stream>>>(part, probs, ph, pl);
    ctx_mfma<<<dim3(C_ / 128, R_, H_), blk, 0, stream>>>(ph, pl, vh, vl, ch, cl);

    gemm_kernel<1><<<dim3(T_ / 128, E_ / 128), blk, 0, stream>>>(
        ch, cl, woh, wol, bo, 1.0f, out, nullptr, nullptr);
}

// Round 2
// 873.581 us; speedup vs baseline: 1.0477x; 1.0477x over previous
//
#include <hip/hip_runtime.h>
#include <math.h>

// Problem constants
#define R_  128
#define C_  256
#define E_  768
#define H_  12
#define DK_ 64
#define T_  (R_*C_)       // 32768 tokens
#define RS_ 8             // split-K over rows in attn kernel
#define LP  40            // LDS pitch for ctx_mfma only (legacy padded layout)

typedef __attribute__((ext_vector_type(8))) short          bf16x8;
typedef __attribute__((ext_vector_type(4))) float          f32x4;
typedef __attribute__((ext_vector_type(4))) unsigned short u16x4;
typedef __attribute__((ext_vector_type(8))) unsigned short u16x8;

struct HL { unsigned short h, l; };

// fp32 -> (hi, lo) bf16 split via truncation. hi+lo represents f with ~2^-16
// relative error; lo = f - hi is exact in fp32 (Sterbenz), then truncated.
__device__ __forceinline__ HL split2(float f) {
    HL o;
    unsigned int u = __float_as_uint(f);
    o.h = (unsigned short)(u >> 16);
    float r = f - __uint_as_float(u & 0xFFFF0000u);
    o.l = (unsigned short)(__float_as_uint(r) >> 16);
    return o;
}

// async global->LDS, 16 B per lane. LDS dest is wave-uniform base + lane*16.
__device__ __forceinline__ void gload16(const void* g, void* l) {
    __builtin_amdgcn_global_load_lds(
        (const __attribute__((address_space(1))) unsigned int*)g,
        (__attribute__((address_space(3))) unsigned int*)l,
        16, 0, 0);
}

// ---------------------------------------------------------------------------
// Pre-split: fp32 -> planar (hi, lo) bf16. 8 elems/thread, exact grids only.
// ---------------------------------------------------------------------------
__global__ __launch_bounds__(256) void split_kernel(
    const float* __restrict__ src,
    unsigned short* __restrict__ h, unsigned short* __restrict__ l)
{
    const size_t i = ((size_t)blockIdx.x * 256 + threadIdx.x) * 8;
    float4 f0 = *(const float4*)(src + i);
    float4 f1 = *(const float4*)(src + i + 4);
    float v[8] = { f0.x, f0.y, f0.z, f0.w, f1.x, f1.y, f1.z, f1.w };
    u16x8 hh, ll;
    #pragma unroll
    for (int j = 0; j < 8; ++j) { HL e = split2(v[j]); hh[j] = e.h; ll[j] = e.l; }
    *(u16x8*)(h + i) = hh;
    *(u16x8*)(l + i) = ll;
}

// ---------------------------------------------------------------------------
// GEMM: Y[m,n] = (sum_k A[m,k]*B[n,k] + bias[n]) * scale
// All operands pre-split planar bf16 (Ah/Al, Bh/Bl). M x 768 x 768,
// 128x128 block tile, BK=32, 256 threads (2x2 waves of 64x64 wave tiles),
// mfma_f32_16x16x32_bf16 with 3-term hi/lo product.
//
// 2-phase double-buffered pipeline (T3 minimum form):
//   prologue: STAGE(buf0, k=0)
//   per K-step: barrier (drains this tile's loads, which were issued before
//   the PREVIOUS step's MFMAs) -> issue STAGE(other buf, next tile) ->
//   ds_read + MFMA current buf. Load latency hides under ~150 MFMAs.
// Staging: wave w stages tile w (AsH/AsL/BsH/BsL) via 8x global_load_lds
// (16 B/lane, 1024 B/instr). LDS swizzle: granule g of row r sits at slot
// g ^ ((r>>1)&3), realized by permuting the per-lane GLOBAL source address
// (LDS dest stays linear, as gload_lds requires); reads XOR the same term
// -> conflict-free ds_read_b128.
// OMODE 0: write split output (Yh, Yl).  OMODE 1: write fp32 Y.
// ---------------------------------------------------------------------------
template<int OMODE>
__global__ __launch_bounds__(256, 2) void gemm_kernel(
    const unsigned short* __restrict__ Ah, const unsigned short* __restrict__ Al,
    const unsigned short* __restrict__ Bh, const unsigned short* __restrict__ Bl,
    const float* __restrict__ bias, float scale,
    float* __restrict__ Y32, unsigned short* __restrict__ Yh, unsigned short* __restrict__ Yl)
{
    __shared__ __align__(16) unsigned short smem[2][16384];   // 64 KB: 2 x 4 x [128][32]

    const int tid  = threadIdx.x;
    const int m0   = blockIdx.x * 128;
    const int n0   = blockIdx.y * 128;
    const int wave = tid >> 6, lane = tid & 63;
    const int wm   = (wave & 1) * 64, wn = (wave >> 1) * 64;
    const int fr   = lane & 15;
    // swizzled read k-offset (ushorts): granule lane>>4 lives at slot ^((fr>>1)&3)
    const int kqs  = (((lane >> 4) ^ ((fr >> 1) & 3)) * 8);

    // staging: lane -> (row = l>>2, slot = l&3); source granule = slot ^ ((l>>3)&3)
    const int lrow = lane >> 2;
    const int gd   = (lane & 3) ^ ((lane >> 3) & 3);
    const unsigned short* gsrc = (wave == 0) ? Ah : (wave == 1) ? Al
                               : (wave == 2) ? Bh : Bl;
    const int rbase = (wave < 2) ? m0 : n0;
    const unsigned short* sp = gsrc + (size_t)(rbase + lrow) * E_ + 8 * gd;
    const int ltoff = wave * 4096;

    f32x4 acc[4][4] = {};

    // prologue: stage K-tile 0 into buffer 0
    {
        unsigned short* lt = &smem[0][ltoff];
        #pragma unroll
        for (int i = 0; i < 8; ++i)
            gload16(sp + (size_t)i * 16 * E_, lt + i * 512);
    }

    int cur = 0;
    for (int k0 = 0; k0 < E_; k0 += 32) {
        __syncthreads();   // drains vmcnt(0): buf[cur] staged; prev reads done
        if (k0 + 32 < E_) {
            unsigned short* lt = &smem[cur ^ 1][ltoff];
            #pragma unroll
            for (int i = 0; i < 8; ++i)
                gload16(sp + k0 + 32 + (size_t)i * 16 * E_, lt + i * 512);
        }
        const unsigned short* AsH = smem[cur];
        const unsigned short* AsL = smem[cur] + 4096;
        const unsigned short* BsH = smem[cur] + 8192;
        const unsigned short* BsL = smem[cur] + 12288;

        bf16x8 a_h[4], a_l[4], b_h[4], b_l[4];
        #pragma unroll
        for (int t = 0; t < 4; ++t) {
            a_h[t] = *(const bf16x8*)&AsH[(wm + t * 16 + fr) * 32 + kqs];
            a_l[t] = *(const bf16x8*)&AsL[(wm + t * 16 + fr) * 32 + kqs];
            b_h[t] = *(const bf16x8*)&BsH[(wn + t * 16 + fr) * 32 + kqs];
            b_l[t] = *(const bf16x8*)&BsL[(wn + t * 16 + fr) * 32 + kqs];
        }
        #pragma unroll
        for (int i = 0; i < 4; ++i)
            #pragma unroll
            for (int j = 0; j < 4; ++j) {
                acc[i][j] = __builtin_amdgcn_mfma_f32_16x16x32_bf16(a_h[i], b_h[j], acc[i][j], 0, 0, 0);
                acc[i][j] = __builtin_amdgcn_mfma_f32_16x16x32_bf16(a_h[i], b_l[j], acc[i][j], 0, 0, 0);
                acc[i][j] = __builtin_amdgcn_mfma_f32_16x16x32_bf16(a_l[i], b_h[j], acc[i][j], 0, 0, 0);
            }
        cur ^= 1;
    }

    // ---- epilogue: per-wave LDS repack -> wide coalesced stores ----
    float* rep = (float*)&smem[0][0] + wave * 1024;   // [16][64] per wave
    const int mr = lane >> 2;
    const int nc = (lane & 3) * 16;
    #pragma unroll
    for (int ti = 0; ti < 4; ++ti) {
        __syncthreads();
        #pragma unroll
        for (int tj = 0; tj < 4; ++tj)
            #pragma unroll
            for (int r = 0; r < 4; ++r)
                rep[((lane >> 4) * 4 + r) * 64 + tj * 16 + fr] = acc[ti][tj][r];
        __syncthreads();
        float v[16];
        #pragma unroll
        for (int c = 0; c < 4; ++c)
            *(float4*)&v[4 * c] = *(const float4*)&rep[mr * 64 + nc + 4 * c];
        const int gm = m0 + wm + ti * 16 + mr;
        const int gn = n0 + wn + nc;
        if constexpr (OMODE == 1) {
            #pragma unroll
            for (int c = 0; c < 4; ++c) {
                float4 bv = *(const float4*)&bias[gn + 4 * c];
                float4 o;
                o.x = (v[4*c+0] + bv.x) * scale; o.y = (v[4*c+1] + bv.y) * scale;
                o.z = (v[4*c+2] + bv.z) * scale; o.w = (v[4*c+3] + bv.w) * scale;
                *(float4*)&Y32[(size_t)gm * E_ + gn + 4 * c] = o;
            }
        } else {
            unsigned short hh[16], ll[16];
            #pragma unroll
            for (int c = 0; c < 4; ++c) {
                float4 bv = *(const float4*)&bias[gn + 4 * c];
                HL e0 = split2((v[4*c+0] + bv.x) * scale);
                HL e1 = split2((v[4*c+1] + bv.y) * scale);
                HL e2 = split2((v[4*c+2] + bv.z) * scale);
                HL e3 = split2((v[4*c+3] + bv.w) * scale);
                hh[4*c+0] = e0.h; ll[4*c+0] = e0.l;
                hh[4*c+1] = e1.h; ll[4*c+1] = e1.l;
                hh[4*c+2] = e2.h; ll[4*c+2] = e2.l;
                hh[4*c+3] = e3.h; ll[4*c+3] = e3.l;
            }
            u16x8 H0, H1, L0, L1;
            #pragma unroll
            for (int j = 0; j < 8; ++j) { H0[j] = hh[j]; H1[j] = hh[8+j]; L0[j] = ll[j]; L1[j] = ll[8+j]; }
            *(u16x8*)&Yh[(size_t)gm * E_ + gn]     = H0;
            *(u16x8*)&Yh[(size_t)gm * E_ + gn + 8] = H1;
            *(u16x8*)&Yl[(size_t)gm * E_ + gn]     = L0;
            *(u16x8*)&Yl[(size_t)gm * E_ + gn + 8] = L1;
        }
    }
}

// ---------------------------------------------------------------------------
// Pooled attention logits, split-K over rows: part[rc,h,i,j] =
//   sum_{r in chunk rc} sum_d q[r,i,h,d] * k[r,j,h,d]
// 128x128 (i,j) tile per block, K-chunk = 16 rows * 64 d = 1024 (32 steps).
// Same 2-phase gload_lds + swizzle staging as gemm_kernel.
// ---------------------------------------------------------------------------
__global__ __launch_bounds__(256, 2) void attn_mfma(
    const unsigned short* __restrict__ Qh, const unsigned short* __restrict__ Ql,
    const unsigned short* __restrict__ Kh, const unsigned short* __restrict__ Kl,
    float* __restrict__ part)
{
    __shared__ __align__(16) unsigned short smem[2][16384];

    const int tid  = threadIdx.x;
    const int i0   = blockIdx.x * 128;
    const int j0   = blockIdx.y * 128;
    const int hz   = blockIdx.z;          // h * RS_ + rc
    const int h    = hz >> 3;
    const int rc   = hz & 7;
    const int wave = tid >> 6, lane = tid & 63;
    const int wm   = (wave & 1) * 64, wn = (wave >> 1) * 64;
    const int fr   = lane & 15;
    const int kqs  = (((lane >> 4) ^ ((fr >> 1) & 3)) * 8);

    const int lrow = lane >> 2;
    const int gd   = (lane & 3) ^ ((lane >> 3) & 3);
    const unsigned short* gsrc = (wave == 0) ? Qh : (wave == 1) ? Ql
                               : (wave == 2) ? Kh : Kl;
    const int rbase = (wave < 2) ? i0 : j0;
    const int ltoff = wave * 4096;
    // per-step source: r = rc*16 + (s>>1), d0 = (s&1)*32
    const unsigned short* sp0 =
        gsrc + ((size_t)(rc * 16 * C_) + rbase + lrow) * E_ + h * DK_ + 8 * gd;

    f32x4 acc[4][4] = {};

    // prologue: stage step 0 into buffer 0
    {
        unsigned short* lt = &smem[0][ltoff];
        #pragma unroll
        for (int i = 0; i < 8; ++i)
            gload16(sp0 + (size_t)i * 16 * E_, lt + i * 512);
    }

    int cur = 0;
    for (int s = 0; s < 32; ++s) {
        __syncthreads();
        if (s + 1 < 32) {
            const int sn = s + 1;
            const unsigned short* sp =
                sp0 + (size_t)(sn >> 1) * C_ * E_ + (sn & 1) * 32;
            unsigned short* lt = &smem[cur ^ 1][ltoff];
            #pragma unroll
            for (int i = 0; i < 8; ++i)
                gload16(sp + (size_t)i * 16 * E_, lt + i * 512);
        }
        const unsigned short* AsH = smem[cur];
        const unsigned short* AsL = smem[cur] + 4096;
        const unsigned short* BsH = smem[cur] + 8192;
        const unsigned short* BsL = smem[cur] + 12288;

        bf16x8 a_h[4], a_l[4], b_h[4], b_l[4];
        #pragma unroll
        for (int t = 0; t < 4; ++t) {
            a_h[t] = *(const bf16x8*)&AsH[(wm + t * 16 + fr) * 32 + kqs];
            a_l[t] = *(const bf16x8*)&AsL[(wm + t * 16 + fr) * 32 + kqs];
            b_h[t] = *(const bf16x8*)&BsH[(wn + t * 16 + fr) * 32 + kqs];
            b_l[t] = *(const bf16x8*)&BsL[(wn + t * 16 + fr) * 32 + kqs];
        }
        #pragma unroll
        for (int i = 0; i < 4; ++i)
            #pragma unroll
            for (int j = 0; j < 4; ++j) {
                acc[i][j] = __builtin_amdgcn_mfma_f32_16x16x32_bf16(a_h[i], b_h[j], acc[i][j], 0, 0, 0);
                acc[i][j] = __builtin_amdgcn_mfma_f32_16x16x32_bf16(a_h[i], b_l[j], acc[i][j], 0, 0, 0);
                acc[i][j] = __builtin_amdgcn_mfma_f32_16x16x32_bf16(a_l[i], b_h[j], acc[i][j], 0, 0, 0);
            }
        cur ^= 1;
    }

    float* rep = (float*)&smem[0][0] + wave * 1024;
    const int mr = lane >> 2;
    const int nc = (lane & 3) * 16;
    #pragma unroll
    for (int ti = 0; ti < 4; ++ti) {
        __syncthreads();
        #pragma unroll
        for (int tj = 0; tj < 4; ++tj)
            #pragma unroll
            for (int r = 0; r < 4; ++r)
                rep[((lane >> 4) * 4 + r) * 64 + tj * 16 + fr] = acc[ti][tj][r];
        __syncthreads();
        const int gi = i0 + wm + ti * 16 + mr;
        const int gj = j0 + wn + nc;
        #pragma unroll
        for (int c = 0; c < 4; ++c) {
            float4 o = *(const float4*)&rep[mr * 64 + nc + 4 * c];
            *(float4*)&part[((size_t)(rc * H_ + h) * C_ + gi) * C_ + gj + 4 * c] = o;
        }
    }
}

// ---------------------------------------------------------------------------
// Reduce RS_ partials + row softmax + write fp32 probs and bf16 split.
// One 256-thread block per (h, i) row.
// ---------------------------------------------------------------------------
__global__ __launch_bounds__(256) void softmax_split(
    const float* __restrict__ part, float* __restrict__ probs,
    unsigned short* __restrict__ ph, unsigned short* __restrict__ pl)
{
    const int row = blockIdx.x;            // h * C_ + i
    const int j = threadIdx.x;
    const int wave = j >> 6, lane = j & 63;

    float s = 0.0f;
    #pragma unroll
    for (int rcn = 0; rcn < RS_; ++rcn)
        s += part[((size_t)rcn * H_ * C_ + row) * C_ + j];

    float m = s;
    #pragma unroll
    for (int off = 32; off > 0; off >>= 1)
        m = fmaxf(m, __shfl_down(m, off, 64));
    __shared__ float redm[4];
    if (lane == 0) redm[wave] = m;
    __syncthreads();
    m = fmaxf(fmaxf(redm[0], redm[1]), fmaxf(redm[2], redm[3]));

    float e = expf(s - m);
    float t = e;
    #pragma unroll
    for (int off = 32; off > 0; off >>= 1)
        t += __shfl_down(t, off, 64);
    __shared__ float reds[4];
    if (lane == 0) reds[wave] = t;
    __syncthreads();
    t = reds[0] + reds[1] + reds[2] + reds[3];

    float p = e / t;
    probs[(size_t)row * C_ + j] = p;
    HL sp = split2(p);
    ph[(size_t)row * C_ + j] = sp.h;
    pl[(size_t)row * C_ + j] = sp.l;
}

// ---------------------------------------------------------------------------
// Context: C[r*C+i, h*64+d] = sum_j P[h,i,j] * V[r*C+j, h*64+d], split output.
// Per (i-block, r, h): M=128(i), N=64(d), K=256(j), BK=32 -> 8 steps.
// V staged transposed into LDS ([d][j]).  (Unchanged this round.)
// ---------------------------------------------------------------------------
__global__ __launch_bounds__(256, 2) void ctx_mfma(
    const unsigned short* __restrict__ Ph, const unsigned short* __restrict__ Pl,
    const unsigned short* __restrict__ Vh, const unsigned short* __restrict__ Vl,
    unsigned short* __restrict__ Ch, unsigned short* __restrict__ Cl)
{
    __shared__ __align__(16) unsigned short smem[15360];   // 30 KB
    unsigned short* PsH = smem;            // [128][LP]
    unsigned short* PsL = smem + 5120;
    unsigned short* VsH = smem + 10240;    // [64][LP]
    unsigned short* VsL = smem + 12800;

    const int tid  = threadIdx.x;
    const int i0   = blockIdx.x * 128;
    const int r    = blockIdx.y;
    const int h    = blockIdx.z;
    const int wave = tid >> 6, lane = tid & 63;
    const int wm   = (wave & 1) * 64, wn = (wave >> 1) * 32;
    const int fr   = lane & 15;
    const int kq   = (lane >> 4) * 8;
    const int srow = tid >> 1;
    const int sk   = (tid & 1) * 16;
    const int vjj  = tid & 31;
    const int vdg  = tid >> 5;             // 0..7

    f32x4 acc[4][2] = {};

    for (int s = 0; s < 8; ++s) {
        const int jb = s * 32;
        const size_t pb = ((size_t)(h * C_) + i0 + srow) * C_ + jb + sk;
        *(u16x8*)&PsH[srow * LP + sk]     = *(const u16x8*)&Ph[pb];
        *(u16x8*)&PsH[srow * LP + sk + 8] = *(const u16x8*)&Ph[pb + 8];
        *(u16x8*)&PsL[srow * LP + sk]     = *(const u16x8*)&Pl[pb];
        *(u16x8*)&PsL[srow * LP + sk + 8] = *(const u16x8*)&Pl[pb + 8];
        const size_t vb = ((size_t)(r * C_) + jb + vjj) * E_ + h * DK_ + vdg * 8;
        u16x8 v_h = *(const u16x8*)&Vh[vb];
        u16x8 v_l = *(const u16x8*)&Vl[vb];
        #pragma unroll
        for (int u = 0; u < 8; ++u) {
            VsH[(vdg * 8 + u) * LP + vjj] = v_h[u];
            VsL[(vdg * 8 + u) * LP + vjj] = v_l[u];
        }
        __syncthreads();

        bf16x8 p_h[4], p_l[4], w_h[2], w_l[2];
        #pragma unroll
        for (int t = 0; t < 4; ++t) {
            p_h[t] = *(const bf16x8*)&PsH[(wm + t * 16 + fr) * LP + kq];
            p_l[t] = *(const bf16x8*)&PsL[(wm + t * 16 + fr) * LP + kq];
        }
        #pragma unroll
        for (int t = 0; t < 2; ++t) {
            w_h[t] = *(const bf16x8*)&VsH[(wn + t * 16 + fr) * LP + kq];
            w_l[t] = *(const bf16x8*)&VsL[(wn + t * 16 + fr) * LP + kq];
        }
        #pragma unroll
        for (int i = 0; i < 4; ++i)
            #pragma unroll
            for (int j = 0; j < 2; ++j) {
                acc[i][j] = __builtin_amdgcn_mfma_f32_16x16x32_bf16(p_h[i], w_h[j], acc[i][j], 0, 0, 0);
                acc[i][j] = __builtin_amdgcn_mfma_f32_16x16x32_bf16(p_h[i], w_l[j], acc[i][j], 0, 0, 0);
                acc[i][j] = __builtin_amdgcn_mfma_f32_16x16x32_bf16(p_l[i], w_h[j], acc[i][j], 0, 0, 0);
            }
        __syncthreads();
    }

    float* rep = (float*)smem + wave * 512;   // [16][32] per wave
    const int mr = lane >> 2;
    const int nc = (lane & 3) * 8;
    #pragma unroll
    for (int ti = 0; ti < 4; ++ti) {
        __syncthreads();
        #pragma unroll
        for (int tj = 0; tj < 2; ++tj)
            #pragma unroll
            for (int rr = 0; rr < 4; ++rr)
                rep[((lane >> 4) * 4 + rr) * 32 + tj * 16 + fr] = acc[ti][tj][rr];
        __syncthreads();
        float v[8];
        *(float4*)&v[0] = *(const float4*)&rep[mr * 32 + nc];
        *(float4*)&v[4] = *(const float4*)&rep[mr * 32 + nc + 4];
        const int gm = r * C_ + i0 + wm + ti * 16 + mr;
        const int gn = h * DK_ + wn + nc;
        u16x8 H8, L8;
        #pragma unroll
        for (int jj = 0; jj < 8; ++jj) { HL e = split2(v[jj]); H8[jj] = e.h; L8[jj] = e.l; }
        *(u16x8*)&Ch[(size_t)gm * E_ + gn] = H8;
        *(u16x8*)&Cl[(size_t)gm * E_ + gn] = L8;
    }
}

// ---------------------------------------------------------------------------
extern "C" void kernel_launch(void* const* d_in, const int* in_sizes, int n_in,
                              void* d_out, int out_size, void* d_ws, size_t ws_size,
                              hipStream_t stream)
{
    (void)in_sizes; (void)n_in; (void)out_size; (void)ws_size;

    const float* x  = (const float*)d_in[0];
    const float* Wq = (const float*)d_in[1];
    const float* bq = (const float*)d_in[2];
    const float* Wk = (const float*)d_in[3];
    const float* bk = (const float*)d_in[4];
    const float* Wv = (const float*)d_in[5];
    const float* bv = (const float*)d_in[6];
    const float* Wo = (const float*)d_in[7];
    const float* bo = (const float*)d_in[8];

    float* out   = (float*)d_out;
    float* probs = out + (size_t)T_ * E_;
    float* part  = out;                     // scratch: out region free until attn

    // ws: 6 planar bf16 buffers of T_*E_ ushorts = 302 MB (unchanged).
    const size_t QN = (size_t)T_ * E_;
    const size_t WN = (size_t)E_ * E_;
    unsigned short* qh = (unsigned short*)d_ws;
    unsigned short* ql = qh + QN;
    unsigned short* kh = ql + QN;
    unsigned short* kl = kh + QN;
    unsigned short* vh = kl + QN;
    unsigned short* vl = vh + QN;
    unsigned short* ph = kh;                 // reuse kh plane (dead after attn)
    unsigned short* pl = kh + (size_t)H_ * C_ * C_;
    unsigned short* ch = qh;                 // reuse q planes (dead after attn)
    unsigned short* cl = ql;

    // Scratch overlays (no new workspace):
    //   xh/xl   -> out region [0, 100.7 MB): dead before attn writes `part`.
    //   wsph/l  -> probs tail region (3.1 MB): dead before softmax writes probs.
    //   woh/wol -> kl plane: dead after attn, survives softmax/ctx/gemm4.
    unsigned short* xh   = (unsigned short*)out;
    unsigned short* xl   = xh + QN;
    unsigned short* wsph = (unsigned short*)probs;
    unsigned short* wspl = wsph + WN;
    unsigned short* woh  = kl;
    unsigned short* wol  = kl + WN;

    const float scaling = 0.125f / sqrtf(128.0f);   // DK^-0.5 / sqrt(R)

    dim3 blk(256);
    const int xblocks = (int)(QN / 2048);   // 8 elems/thread, exact
    const int wblocks = (int)(WN / 2048);

    split_kernel<<<dim3(xblocks), blk, 0, stream>>>(x, xh, xl);

    split_kernel<<<dim3(wblocks), blk, 0, stream>>>(Wq, wsph, wspl);
    gemm_kernel<0><<<dim3(T_ / 128, E_ / 128), blk, 0, stream>>>(
        xh, xl, wsph, wspl, bq, scaling, nullptr, qh, ql);

    split_kernel<<<dim3(wblocks), blk, 0, stream>>>(Wk, wsph, wspl);
    gemm_kernel<0><<<dim3(T_ / 128, E_ / 128), blk, 0, stream>>>(
        xh, xl, wsph, wspl, bk, 1.0f, nullptr, kh, kl);

    split_kernel<<<dim3(wblocks), blk, 0, stream>>>(Wv, wsph, wspl);
    gemm_kernel<0><<<dim3(T_ / 128, E_ / 128), blk, 0, stream>>>(
        xh, xl, wsph, wspl, bv, 1.0f, nullptr, vh, vl);

    attn_mfma<<<dim3(C_ / 128, C_ / 128, H_ * RS_), blk, 0, stream>>>(qh, ql, kh, kl, part);

    split_kernel<<<dim3(wblocks), blk, 0, stream>>>(Wo, woh, wol);   // kl plane now dead

    softmax_split<<<dim3(H_ * C_), blk, 0, stream>>>(part, probs, ph, pl);
    ctx_mfma<<<dim3(C_ / 128, R_, H_), blk, 0, stream>>>(ph, pl, vh, vl, ch, cl);

    gemm_kernel<1><<<dim3(T_ / 128, E_ / 128), blk, 0, stream>>>(
        ch, cl, woh, wol, bo, 1.0f, out, nullptr, nullptr);
}